// Round 2
// baseline (1272.871 us; speedup 1.0000x reference)
//
#include <hip/hip_runtime.h>
#include <cstdint>

#define TFACTOR 0.05f
#define BN_EPS 1e-5f

typedef unsigned short u16;
using frag_ab = __attribute__((ext_vector_type(8))) short;  // 8 bf16
using frag_cd = __attribute__((ext_vector_type(4))) float;  // 4 fp32

#define M_TOTAL 200704      // 64*56*56
#define HW_IMG  3136        // 56*56

__device__ __forceinline__ float bf2f(unsigned int u) {
    return __uint_as_float(u << 16);
}
__device__ __forceinline__ u16 f2bf(float f) {
    unsigned int u = __float_as_uint(f);
    unsigned int r = (u + 0x7fffu + ((u >> 16) & 1u)) >> 16;
    return (u16)r;
}

// global -> LDS direct DMA, 16 B per lane. LDS dest must be wave-uniform
// base; lane i lands at base + i*16. Proper addrspace casts (no integer
// truncation of the flat pointer).
__device__ __forceinline__ void gl_lds16(const u16* g, u16* l) {
    __builtin_amdgcn_global_load_lds(
        (const __attribute__((address_space(1))) void*)g,
        (__attribute__((address_space(3))) void*)l,
        16, 0, 0);
}

// ---------------- quantization ----------------
__global__ void k_absmax(const float* __restrict__ w, int n, float* dmax) {
    int i = blockIdx.x * blockDim.x + threadIdx.x;
    float m = 0.f;
    for (; i < n; i += gridDim.x * blockDim.x) m = fmaxf(m, fabsf(w[i]));
    #pragma unroll
    for (int off = 32; off > 0; off >>= 1) m = fmaxf(m, __shfl_down(m, off));
    if ((threadIdx.x & 63) == 0) atomicMax((unsigned int*)dmax, __float_as_uint(m));
}

__global__ void k_qsum(const float* __restrict__ w, int n, const float* dmax,
                       float* dsum, float* dcnt) {
    float th = TFACTOR * (*dmax);
    int i = blockIdx.x * blockDim.x + threadIdx.x;
    float s = 0.f, c = 0.f;
    for (; i < n; i += gridDim.x * blockDim.x) {
        float a = fabsf(w[i]);
        if (a >= th) { s += a; c += 1.f; }
    }
    #pragma unroll
    for (int off = 32; off > 0; off >>= 1) {
        s += __shfl_down(s, off);
        c += __shfl_down(c, off);
    }
    if ((threadIdx.x & 63) == 0) { atomicAdd(dsum, s); atomicAdd(dcnt, c); }
}

// w: [co][ci][3][3] fp32  ->  wq: [kh][kw][co][ci] bf16
__global__ void k_tern(const float* __restrict__ w, int n, const float* dmax,
                       const float* dsum, const float* dcnt, u16* __restrict__ wq) {
    int idx = blockIdx.x * blockDim.x + threadIdx.x;
    if (idx >= n) return;
    float th = TFACTOR * (*dmax);
    float W = (*dsum) / fmaxf(*dcnt, 1.f);
    int kw = idx % 3;
    int t = idx / 3;
    int kh = t % 3; t /= 3;
    int ci = t % 256;
    int co = t / 256;
    float v = w[idx];
    float q = (v >= th) ? W : ((v < -th) ? -W : 0.f);
    wq[((size_t)(kh * 3 + kw) * 256 + co) * 256 + ci] = f2bf(q);
}

// ---------------- NCHW fp32 -> NHWC bf16 ----------------
__global__ void k_to_nhwc(const float* __restrict__ X, u16* __restrict__ Y) {
    __shared__ float tile[128][65];
    int t = threadIdx.x;
    int m0 = blockIdx.x * 128, c0 = blockIdx.y * 64;
    #pragma unroll
    for (int it = 0; it < 8; ++it) {
        int flat4 = it * 256 + t;
        int corow = flat4 >> 5;          // 0..63
        int m4 = (flat4 & 31) * 4;       // 0..124
        int m = m0 + m4;
        int n = m / HW_IMG; int s = m - n * HW_IMG;
        float4 v = *(const float4*)(X + ((size_t)(n * 256 + c0 + corow)) * HW_IMG + s);
        tile[m4 + 0][corow] = v.x; tile[m4 + 1][corow] = v.y;
        tile[m4 + 2][corow] = v.z; tile[m4 + 3][corow] = v.w;
    }
    __syncthreads();
    #pragma unroll
    for (int j = 0; j < 32; ++j) {
        int flat = j * 256 + t;
        int m = flat >> 6;               // 0..127
        int c = flat & 63;
        Y[(size_t)(m0 + m) * 256 + c0 + c] = f2bf(tile[m][c]);
    }
}

// ---------------- conv as implicit GEMM (m97 structure) ----------------
// Ax: [M][256] bf16 NHWC, Wq: [9][256co][256ci] bf16, Out: [M][256] bf16
__global__ void __launch_bounds__(256)
k_conv(const u16* __restrict__ Ax, const u16* __restrict__ Wq,
       u16* __restrict__ Out, const u16* __restrict__ zbuf) {
    __shared__ u16 Asm[128 * 64];
    __shared__ u16 Bsm[128 * 64];
    const int t = threadIdx.x;
    const int lane = t & 63, wv = t >> 6;
    const int bm = blockIdx.x >> 1;
    const int co0 = (blockIdx.x & 1) * 128;
    const int wm = wv >> 1, wn = wv & 1;

    int rowA[4], gA[4], hA[4], wA[4], nA[4];
    #pragma unroll
    for (int j = 0; j < 4; ++j) {
        int r = wv * 32 + j * 8 + (lane >> 3);
        rowA[j] = r;
        gA[j] = (lane & 7) ^ (r & 7);            // XOR-swizzled chunk slot
        int m = bm * 128 + r;
        int n = m / HW_IMG; int rem = m - n * HW_IMG;
        int h = rem / 56; int w = rem - h * 56;
        nA[j] = n; hA[j] = h; wA[j] = w;
    }

    frag_cd acc[4][4];
    #pragma unroll
    for (int i = 0; i < 4; ++i)
        #pragma unroll
        for (int j2 = 0; j2 < 4; ++j2)
            #pragma unroll
            for (int e = 0; e < 4; ++e) acc[i][j2][e] = 0.f;

    for (int pass = 0; pass < 9; ++pass) {
        int dh = pass / 3 - 1, dw = pass % 3 - 1;
        const u16* pA[4]; const u16* pB[4];
        #pragma unroll
        for (int j = 0; j < 4; ++j) {
            int hh = hA[j] + dh, ww = wA[j] + dw;
            bool valid = ((unsigned)hh < 56u) && ((unsigned)ww < 56u);
            const u16* p = valid
                ? (Ax + ((size_t)((nA[j] * 56 + hh) * 56 + ww)) * 256)
                : zbuf;
            pA[j] = p + gA[j] * 8;
            pB[j] = Wq + ((size_t)(pass * 256 + co0 + rowA[j])) * 256 + gA[j] * 8;
        }
        for (int kc = 0; kc < 4; ++kc) {
            __syncthreads();
            #pragma unroll
            for (int j = 0; j < 4; ++j) {
                gl_lds16(pA[j] + kc * 64, Asm + (wv * 4 + j) * 512);
                gl_lds16(pB[j] + kc * 64, Bsm + (wv * 4 + j) * 512);
            }
            __syncthreads();
            #pragma unroll
            for (int kk = 0; kk < 2; ++kk) {
                frag_ab a[4], b[4];
                int q = lane >> 4;
                int c = kk * 4 + q;
                #pragma unroll
                for (int i = 0; i < 4; ++i) {
                    int mrow = wm * 64 + i * 16 + (lane & 15);
                    a[i] = *(const frag_ab*)(Asm + mrow * 64 + ((c ^ (mrow & 7)) * 8));
                    int nrow = wn * 64 + i * 16 + (lane & 15);
                    b[i] = *(const frag_ab*)(Bsm + nrow * 64 + ((c ^ (nrow & 7)) * 8));
                }
                #pragma unroll
                for (int i = 0; i < 4; ++i)
                    #pragma unroll
                    for (int jn = 0; jn < 4; ++jn)
                        acc[i][jn] = __builtin_amdgcn_mfma_f32_16x16x32_bf16(
                            a[i], b[jn], acc[i][jn], 0, 0, 0);
            }
        }
    }

    // epilogue: C/D layout col=lane&15, row=(lane>>4)*4+reg
    size_t mbase = (size_t)bm * 128 + wm * 64;
    #pragma unroll
    for (int i = 0; i < 4; ++i) {
        #pragma unroll
        for (int jn = 0; jn < 4; ++jn) {
            int coc = co0 + wn * 64 + jn * 16 + (lane & 15);
            #pragma unroll
            for (int r = 0; r < 4; ++r) {
                size_t mo = mbase + i * 16 + (lane >> 4) * 4 + r;
                Out[mo * 256 + coc] = f2bf(acc[i][jn][r]);
            }
        }
    }
}

// ---------------- BN stats: per-channel sum / sumsq ----------------
__global__ void k_bnstats(const u16* __restrict__ X, float* __restrict__ sum,
                          float* __restrict__ sumsq) {
    int co = threadIdx.x;
    int m0 = blockIdx.x * 98;
    float s = 0.f, q = 0.f;
    for (int k = 0; k < 98; ++k) {
        float v = bf2f(X[(size_t)(m0 + k) * 256 + co]);
        s += v; q += v * v;
    }
    atomicAdd(&sum[co], s);
    atomicAdd(&sumsq[co], q);
}

// ---------------- BN + ReLU in place (bf16) ----------------
__global__ void k_bnrelu(u16* __restrict__ X, const float* __restrict__ sum,
                         const float* __restrict__ sumsq,
                         const float* __restrict__ gamma, const float* __restrict__ beta) {
    __shared__ float sc[256], sh[256];
    int t = threadIdx.x;
    {
        float mean = sum[t] * (1.f / (float)M_TOTAL);
        float var = sumsq[t] * (1.f / (float)M_TOTAL) - mean * mean;
        float s = rsqrtf(var + BN_EPS) * gamma[t];
        sc[t] = s; sh[t] = beta[t] - mean * s;
    }
    __syncthreads();
    size_t idx = (size_t)blockIdx.x * 256 + t;
    int c4 = ((int)(idx & 63)) * 4;
    size_t m = idx >> 6;
    uint2 v = *(uint2*)(X + m * 256 + c4);
    float f0 = bf2f(v.x & 0xffffu), f1 = bf2f(v.x >> 16);
    float f2 = bf2f(v.y & 0xffffu), f3 = bf2f(v.y >> 16);
    f0 = fmaxf(f0 * sc[c4 + 0] + sh[c4 + 0], 0.f);
    f1 = fmaxf(f1 * sc[c4 + 1] + sh[c4 + 1], 0.f);
    f2 = fmaxf(f2 * sc[c4 + 2] + sh[c4 + 2], 0.f);
    f3 = fmaxf(f3 * sc[c4 + 3] + sh[c4 + 3], 0.f);
    uint2 o;
    o.x = ((unsigned)f2bf(f1) << 16) | f2bf(f0);
    o.y = ((unsigned)f2bf(f3) << 16) | f2bf(f2);
    *(uint2*)(X + m * 256 + c4) = o;
}

// ---------------- final: BN2 + residual + ReLU, NHWC bf16 -> NCHW fp32 ----------------
__global__ void k_final(const u16* __restrict__ O2, const float* __restrict__ X,
                        const float* __restrict__ sum, const float* __restrict__ sumsq,
                        const float* __restrict__ gamma, const float* __restrict__ beta,
                        float* __restrict__ Out) {
    __shared__ float tile[64][129];
    __shared__ float sc[64], sh[64];
    int t = threadIdx.x;
    int m0 = blockIdx.x * 128, c0 = blockIdx.y * 64;
    if (t < 64) {
        int c = c0 + t;
        float mean = sum[c] * (1.f / (float)M_TOTAL);
        float var = sumsq[c] * (1.f / (float)M_TOTAL) - mean * mean;
        float s = rsqrtf(var + BN_EPS) * gamma[c];
        sc[t] = s; sh[t] = beta[c] - mean * s;
    }
    __syncthreads();
    #pragma unroll
    for (int it = 0; it < 8; ++it) {
        int flat4 = it * 256 + t;
        int r = flat4 >> 4;              // 0..127
        int c4 = (flat4 & 15) * 4;       // 0..60
        uint2 v = *(const uint2*)(O2 + (size_t)(m0 + r) * 256 + c0 + c4);
        tile[c4 + 0][r] = bf2f(v.x & 0xffffu) * sc[c4 + 0] + sh[c4 + 0];
        tile[c4 + 1][r] = bf2f(v.x >> 16) * sc[c4 + 1] + sh[c4 + 1];
        tile[c4 + 2][r] = bf2f(v.y & 0xffffu) * sc[c4 + 2] + sh[c4 + 2];
        tile[c4 + 3][r] = bf2f(v.y >> 16) * sc[c4 + 3] + sh[c4 + 3];
    }
    __syncthreads();
    #pragma unroll
    for (int it = 0; it < 8; ++it) {
        int flat = it * 256 + t;
        int co = flat >> 5;              // 0..63
        int ml = flat & 31;
        #pragma unroll
        for (int j = 0; j < 4; ++j) {
            int m = m0 + ml + j * 32;
            int n = m / HW_IMG; int s = m - n * HW_IMG;
            size_t a = ((size_t)(n * 256 + c0 + co)) * HW_IMG + s;
            Out[a] = fmaxf(tile[co][ml + j * 32] + X[a], 0.f);
        }
    }
}

extern "C" void kernel_launch(void* const* d_in, const int* in_sizes, int n_in,
                              void* d_out, int out_size, void* d_ws, size_t ws_size,
                              hipStream_t stream) {
    const float* x  = (const float*)d_in[0];
    const float* w1 = (const float*)d_in[1];
    const float* g1 = (const float*)d_in[2];
    const float* b1 = (const float*)d_in[3];
    const float* w2 = (const float*)d_in[4];
    const float* g2 = (const float*)d_in[5];
    const float* b2 = (const float*)d_in[6];
    float* out = (float*)d_out;
    char* ws = (char*)d_ws;

    // d_out (205,520,896 B) doubles as scratch for the two NHWC bf16
    // intermediates (exactly 2 x 102,760,448 B); it is fully overwritten
    // by k_final at the end. ws usage: ~103 MB total.
    u16* xh = (u16*)d_out;                        // NHWC bf16 input
    u16* y1 = xh + (size_t)M_TOTAL * 256;         // conv1 out -> BN+ReLU in place

    u16* zbuf = (u16*)ws;                         // 1024 B of zeros
    float* q1max = (float*)(ws + 1024);
    float* q1sum = q1max + 1;
    float* q1cnt = q1max + 2;
    float* q2max = (float*)(ws + 1088);
    float* q2sum = q2max + 1;
    float* q2cnt = q2max + 2;
    float* s1  = (float*)(ws + 1152);
    float* sq1 = s1 + 256;
    float* s2  = sq1 + 256;
    float* sq2 = s2 + 256;
    u16* wq1 = (u16*)(ws + 8192);                 // [9][256][256] bf16
    u16* wq2 = wq1 + (size_t)9 * 256 * 256;
    u16* out2 = (u16*)(ws + 2367488);             // conv2 out, 102,760,448 B

    hipMemsetAsync(ws, 0, 8192, stream);          // zbuf + all stats

    const int nw = 256 * 256 * 9;
    k_absmax<<<512, 256, 0, stream>>>(w1, nw, q1max);
    k_absmax<<<512, 256, 0, stream>>>(w2, nw, q2max);
    k_qsum<<<512, 256, 0, stream>>>(w1, nw, q1max, q1sum, q1cnt);
    k_qsum<<<512, 256, 0, stream>>>(w2, nw, q2max, q2sum, q2cnt);
    k_tern<<<(nw + 255) / 256, 256, 0, stream>>>(w1, nw, q1max, q1sum, q1cnt, wq1);
    k_tern<<<(nw + 255) / 256, 256, 0, stream>>>(w2, nw, q2max, q2sum, q2cnt, wq2);

    k_to_nhwc<<<dim3(1568, 4), 256, 0, stream>>>(x, xh);

    k_conv<<<3136, 256, 0, stream>>>(xh, wq1, y1, zbuf);
    k_bnstats<<<2048, 256, 0, stream>>>(y1, s1, sq1);
    k_bnrelu<<<50176, 256, 0, stream>>>(y1, s1, sq1, g1, b1);

    k_conv<<<3136, 256, 0, stream>>>(y1, wq2, out2, zbuf);
    k_bnstats<<<2048, 256, 0, stream>>>(out2, s2, sq2);
    k_final<<<dim3(1568, 4), 256, 0, stream>>>(out2, x, s2, sq2, g2, b2, out);
}

// Round 3
// 967.643 us; speedup vs baseline: 1.3154x; 1.3154x over previous
//
#include <hip/hip_runtime.h>
#include <cstdint>

#define TFACTOR 0.05f
#define BN_EPS 1e-5f

typedef unsigned short u16;
using frag_ab = __attribute__((ext_vector_type(8))) short;  // 8 bf16
using frag_cd = __attribute__((ext_vector_type(4))) float;  // 4 fp32

#define M_TOTAL 200704      // 64*56*56
#define HW_IMG  3136        // 56*56

__device__ __forceinline__ float bf2f(unsigned int u) {
    return __uint_as_float(u << 16);
}
__device__ __forceinline__ u16 f2bf(float f) {
    unsigned int u = __float_as_uint(f);
    unsigned int r = (u + 0x7fffu + ((u >> 16) & 1u)) >> 16;
    return (u16)r;
}

__device__ __forceinline__ void gl_lds16(const u16* g, u16* l) {
    __builtin_amdgcn_global_load_lds(
        (const __attribute__((address_space(1))) void*)g,
        (__attribute__((address_space(3))) void*)l,
        16, 0, 0);
}

// ---------------- quantization (both weights per launch) ----------------
__global__ void k_absmax(const float* __restrict__ w1, const float* __restrict__ w2,
                         int n, float* m1, float* m2) {
    const float* w = (blockIdx.x < 256) ? w1 : w2;
    float* dm = (blockIdx.x < 256) ? m1 : m2;
    int bx = blockIdx.x & 255;
    float m = 0.f;
    for (int i = bx * 256 + threadIdx.x; i < n; i += 256 * 256)
        m = fmaxf(m, fabsf(w[i]));
    #pragma unroll
    for (int off = 32; off > 0; off >>= 1) m = fmaxf(m, __shfl_down(m, off));
    if ((threadIdx.x & 63) == 0) atomicMax((unsigned int*)dm, __float_as_uint(m));
}

__global__ void k_qsum(const float* __restrict__ w1, const float* __restrict__ w2,
                       int n, const float* m1, const float* m2,
                       float* s1, float* c1, float* s2, float* c2) {
    const float* w = (blockIdx.x < 256) ? w1 : w2;
    float th = TFACTOR * ((blockIdx.x < 256) ? *m1 : *m2);
    float* ds = (blockIdx.x < 256) ? s1 : s2;
    float* dc = (blockIdx.x < 256) ? c1 : c2;
    int bx = blockIdx.x & 255;
    float s = 0.f, c = 0.f;
    for (int i = bx * 256 + threadIdx.x; i < n; i += 256 * 256) {
        float a = fabsf(w[i]);
        if (a >= th) { s += a; c += 1.f; }
    }
    #pragma unroll
    for (int off = 32; off > 0; off >>= 1) {
        s += __shfl_down(s, off);
        c += __shfl_down(c, off);
    }
    if ((threadIdx.x & 63) == 0) { atomicAdd(ds, s); atomicAdd(dc, c); }
}

// w: [co][ci][3][3] fp32  ->  wq: [kh][kw][co][ci] bf16  (both weights)
__global__ void k_tern(const float* __restrict__ w1, const float* __restrict__ w2,
                       int n, const float* m1, const float* s1, const float* c1,
                       const float* m2, const float* s2, const float* c2,
                       u16* __restrict__ wq1, u16* __restrict__ wq2) {
    int gid = blockIdx.x * blockDim.x + threadIdx.x;
    bool second = gid >= n;
    int idx = second ? gid - n : gid;
    const float* w = second ? w2 : w1;
    u16* wq = second ? wq2 : wq1;
    float th = TFACTOR * (second ? *m2 : *m1);
    float W = (second ? *s2 : *s1) / fmaxf(second ? *c2 : *c1, 1.f);
    int kw = idx % 3;
    int t = idx / 3;
    int kh = t % 3; t /= 3;
    int ci = t % 256;
    int co = t / 256;
    float v = w[idx];
    float q = (v >= th) ? W : ((v < -th) ? -W : 0.f);
    wq[((size_t)(kh * 3 + kw) * 256 + co) * 256 + ci] = f2bf(q);
}

// ---------------- NCHW fp32 -> NHWC bf16 ----------------
__global__ void k_to_nhwc(const float* __restrict__ X, u16* __restrict__ Y) {
    __shared__ float tile[128][65];
    int t = threadIdx.x;
    int m0 = blockIdx.x * 128, c0 = blockIdx.y * 64;
    #pragma unroll
    for (int it = 0; it < 8; ++it) {
        int flat4 = it * 256 + t;
        int corow = flat4 >> 5;          // 0..63
        int m4 = (flat4 & 31) * 4;       // 0..124
        int m = m0 + m4;
        int n = m / HW_IMG; int s = m - n * HW_IMG;
        float4 v = *(const float4*)(X + ((size_t)(n * 256 + c0 + corow)) * HW_IMG + s);
        tile[m4 + 0][corow] = v.x; tile[m4 + 1][corow] = v.y;
        tile[m4 + 2][corow] = v.z; tile[m4 + 3][corow] = v.w;
    }
    __syncthreads();
    #pragma unroll
    for (int it = 0; it < 8; ++it) {
        int flat = it * 256 + t;         // 2048 quads: 128 m x 16 c-quads
        int m = flat >> 4;               // 0..127
        int c4 = (flat & 15) * 4;        // 0..60
        uint2 o;
        o.x = ((unsigned)f2bf(tile[m][c4 + 1]) << 16) | f2bf(tile[m][c4 + 0]);
        o.y = ((unsigned)f2bf(tile[m][c4 + 3]) << 16) | f2bf(tile[m][c4 + 2]);
        *(uint2*)(Y + (size_t)(m0 + m) * 256 + c0 + c4) = o;
    }
}

// ---------------- conv as implicit GEMM + fused BN-stats ----------------
// Ax: [M][256] bf16 NHWC, Wq: [9][256co][256ci] bf16, Out: [M][256] bf16
// XCD-slab swizzle: blocks b with b&7==x form XCD x's slab of 196 contiguous
// m-tiles; the two co-halves of one m-tile run back-to-back on the same XCD
// so A is fetched into that XCD's L2 once, not 8x.
__global__ void __launch_bounds__(256)
k_conv(const u16* __restrict__ Ax, const u16* __restrict__ Wq,
       u16* __restrict__ Out, const u16* __restrict__ zbuf,
       float* __restrict__ bsum, float* __restrict__ bsq) {
    __shared__ u16 Asm[128 * 64];
    __shared__ u16 Bsm[128 * 64];
    const int t = threadIdx.x;
    const int lane = t & 63, wv = t >> 6;
    const int b = blockIdx.x;
    const int xcd = b & 7;
    const int ii = b >> 3;                 // 0..391
    const int bm = xcd * 196 + (ii >> 1);  // 0..1567
    const int co0 = (ii & 1) << 7;
    const int wm = wv >> 1, wn = wv & 1;

    int rowA[4], gA[4], hA[4], wA[4], nA[4];
    #pragma unroll
    for (int j = 0; j < 4; ++j) {
        int r = wv * 32 + j * 8 + (lane >> 3);
        rowA[j] = r;
        gA[j] = (lane & 7) ^ (r & 7);            // XOR-swizzled chunk slot
        int m = bm * 128 + r;
        int n = m / HW_IMG; int rem = m - n * HW_IMG;
        int h = rem / 56; int w = rem - h * 56;
        nA[j] = n; hA[j] = h; wA[j] = w;
    }

    frag_cd acc[4][4];
    #pragma unroll
    for (int i = 0; i < 4; ++i)
        #pragma unroll
        for (int j2 = 0; j2 < 4; ++j2)
            #pragma unroll
            for (int e = 0; e < 4; ++e) acc[i][j2][e] = 0.f;

    for (int pass = 0; pass < 9; ++pass) {
        int dh = pass / 3 - 1, dw = pass % 3 - 1;
        const u16* pA[4]; const u16* pB[4];
        #pragma unroll
        for (int j = 0; j < 4; ++j) {
            int hh = hA[j] + dh, ww = wA[j] + dw;
            bool valid = ((unsigned)hh < 56u) && ((unsigned)ww < 56u);
            const u16* p = valid
                ? (Ax + ((size_t)((nA[j] * 56 + hh) * 56 + ww)) * 256)
                : zbuf;
            pA[j] = p + gA[j] * 8;
            pB[j] = Wq + ((size_t)(pass * 256 + co0 + rowA[j])) * 256 + gA[j] * 8;
        }
        for (int kc = 0; kc < 4; ++kc) {
            __syncthreads();
            #pragma unroll
            for (int j = 0; j < 4; ++j) {
                gl_lds16(pA[j] + kc * 64, Asm + (wv * 4 + j) * 512);
                gl_lds16(pB[j] + kc * 64, Bsm + (wv * 4 + j) * 512);
            }
            __syncthreads();
            #pragma unroll
            for (int kk = 0; kk < 2; ++kk) {
                frag_ab a[4], bfr[4];
                int q = lane >> 4;
                int c = kk * 4 + q;
                #pragma unroll
                for (int i = 0; i < 4; ++i) {
                    int mrow = wm * 64 + i * 16 + (lane & 15);
                    a[i] = *(const frag_ab*)(Asm + mrow * 64 + ((c ^ (mrow & 7)) * 8));
                    int nrow = wn * 64 + i * 16 + (lane & 15);
                    bfr[i] = *(const frag_ab*)(Bsm + nrow * 64 + ((c ^ (nrow & 7)) * 8));
                }
                #pragma unroll
                for (int i = 0; i < 4; ++i)
                    #pragma unroll
                    for (int jn = 0; jn < 4; ++jn)
                        acc[i][jn] = __builtin_amdgcn_mfma_f32_16x16x32_bf16(
                            a[i], bfr[jn], acc[i][jn], 0, 0, 0);
            }
        }
    }

    // epilogue: C/D layout col=lane&15, row=(lane>>4)*4+reg
    // also accumulate per-channel sum / sumsq of the (bf16-rounded) outputs
    float psum[4] = {0.f, 0.f, 0.f, 0.f};
    float psq[4]  = {0.f, 0.f, 0.f, 0.f};
    size_t mbase = (size_t)bm * 128 + wm * 64;
    #pragma unroll
    for (int i = 0; i < 4; ++i) {
        #pragma unroll
        for (int jn = 0; jn < 4; ++jn) {
            int coc = co0 + wn * 64 + jn * 16 + (lane & 15);
            #pragma unroll
            for (int r = 0; r < 4; ++r) {
                size_t mo = mbase + i * 16 + (lane >> 4) * 4 + r;
                u16 h = f2bf(acc[i][jn][r]);
                Out[mo * 256 + coc] = h;
                float v = bf2f(h);
                psum[jn] += v; psq[jn] += v * v;
            }
        }
    }
    // reduce stats: butterfly over the 4 lane-groups sharing a channel,
    // then cross-wave via LDS (aliased over Asm — all LDS reads are done).
    __syncthreads();
    float* red = (float*)Asm;            // [0..255]=sum slots, [256..511]=sq
    #pragma unroll
    for (int jn = 0; jn < 4; ++jn) {
        float s = psum[jn], q = psq[jn];
        s += __shfl_down(s, 32); s += __shfl_down(s, 16);
        q += __shfl_down(q, 32); q += __shfl_down(q, 16);
        if (lane < 16) {
            red[wv * 64 + jn * 16 + lane] = s;
            red[256 + wv * 64 + jn * 16 + lane] = q;
        }
    }
    __syncthreads();
    if (t < 128) {
        int wnq = t >> 6, cc = t & 63;
        float s = red[wnq * 64 + cc] + red[(2 + wnq) * 64 + cc];
        float q = red[256 + wnq * 64 + cc] + red[256 + (2 + wnq) * 64 + cc];
        atomicAdd(&bsum[co0 + t], s);
        atomicAdd(&bsq[co0 + t], q);
    }
}

// ---------------- BN + ReLU in place (bf16), uint4 = 8 elems/thread -------
__global__ void k_bnrelu(u16* __restrict__ X, const float* __restrict__ sum,
                         const float* __restrict__ sumsq,
                         const float* __restrict__ gamma, const float* __restrict__ beta) {
    __shared__ float sc[256], sh[256];
    int t = threadIdx.x;
    {
        float mean = sum[t] * (1.f / (float)M_TOTAL);
        float var = sumsq[t] * (1.f / (float)M_TOTAL) - mean * mean;
        float s = rsqrtf(var + BN_EPS) * gamma[t];
        sc[t] = s; sh[t] = beta[t] - mean * s;
    }
    __syncthreads();
    const size_t N8 = (size_t)M_TOTAL * 32;   // elements/8
    for (size_t i = (size_t)blockIdx.x * 256 + t; i < N8; i += (size_t)gridDim.x * 256) {
        int c8 = ((int)(i & 31)) * 8;
        uint4 v = *(uint4*)(X + i * 8);
        unsigned r[4] = {v.x, v.y, v.z, v.w};
        uint4 o;
        unsigned* po = (unsigned*)&o;
        #pragma unroll
        for (int k = 0; k < 4; ++k) {
            float f0 = bf2f(r[k] & 0xffffu) * sc[c8 + 2 * k] + sh[c8 + 2 * k];
            float f1 = bf2f(r[k] >> 16) * sc[c8 + 2 * k + 1] + sh[c8 + 2 * k + 1];
            po[k] = ((unsigned)f2bf(fmaxf(f1, 0.f)) << 16) | f2bf(fmaxf(f0, 0.f));
        }
        *(uint4*)(X + i * 8) = o;
    }
}

// ------ final: BN2 + residual + ReLU, NHWC bf16 -> NCHW fp32 (float4) -----
__global__ void k_final(const u16* __restrict__ O2, const float* __restrict__ X,
                        const float* __restrict__ sum, const float* __restrict__ sumsq,
                        const float* __restrict__ gamma, const float* __restrict__ beta,
                        float* __restrict__ Out) {
    __shared__ float tile[64][129];
    __shared__ float sc[64], sh[64];
    int t = threadIdx.x;
    int m0 = blockIdx.x * 128, c0 = blockIdx.y * 64;
    if (t < 64) {
        int c = c0 + t;
        float mean = sum[c] * (1.f / (float)M_TOTAL);
        float var = sumsq[c] * (1.f / (float)M_TOTAL) - mean * mean;
        float s = rsqrtf(var + BN_EPS) * gamma[c];
        sc[t] = s; sh[t] = beta[c] - mean * s;
    }
    __syncthreads();
    #pragma unroll
    for (int it = 0; it < 8; ++it) {
        int flat4 = it * 256 + t;
        int r = flat4 >> 4;              // 0..127
        int c4 = (flat4 & 15) * 4;       // 0..60
        uint2 v = *(const uint2*)(O2 + (size_t)(m0 + r) * 256 + c0 + c4);
        tile[c4 + 0][r] = bf2f(v.x & 0xffffu) * sc[c4 + 0] + sh[c4 + 0];
        tile[c4 + 1][r] = bf2f(v.x >> 16) * sc[c4 + 1] + sh[c4 + 1];
        tile[c4 + 2][r] = bf2f(v.y & 0xffffu) * sc[c4 + 2] + sh[c4 + 2];
        tile[c4 + 3][r] = bf2f(v.y >> 16) * sc[c4 + 3] + sh[c4 + 3];
    }
    __syncthreads();
    #pragma unroll
    for (int it = 0; it < 8; ++it) {
        int flat = it * 256 + t;         // 2048 float4 tasks: 64 co x 32 m-quads
        int co = flat >> 5;              // 0..63
        int m4 = (flat & 31) * 4;        // 0..124 (HW_IMG%4==0 -> same image)
        int m = m0 + m4;
        int n = m / HW_IMG; int s = m - n * HW_IMG;
        size_t a = ((size_t)(n * 256 + c0 + co)) * HW_IMG + s;
        float4 xv = *(const float4*)(X + a);
        float4 o;
        o.x = fmaxf(tile[co][m4 + 0] + xv.x, 0.f);
        o.y = fmaxf(tile[co][m4 + 1] + xv.y, 0.f);
        o.z = fmaxf(tile[co][m4 + 2] + xv.z, 0.f);
        o.w = fmaxf(tile[co][m4 + 3] + xv.w, 0.f);
        *(float4*)(Out + a) = o;
    }
}

extern "C" void kernel_launch(void* const* d_in, const int* in_sizes, int n_in,
                              void* d_out, int out_size, void* d_ws, size_t ws_size,
                              hipStream_t stream) {
    const float* x  = (const float*)d_in[0];
    const float* w1 = (const float*)d_in[1];
    const float* g1 = (const float*)d_in[2];
    const float* b1 = (const float*)d_in[3];
    const float* w2 = (const float*)d_in[4];
    const float* g2 = (const float*)d_in[5];
    const float* b2 = (const float*)d_in[6];
    float* out = (float*)d_out;
    char* ws = (char*)d_ws;

    // d_out doubles as scratch for the two NHWC bf16 intermediates
    // (exactly 2 x 102,760,448 B); fully overwritten by k_final.
    u16* xh = (u16*)d_out;                        // NHWC bf16 input
    u16* y1 = xh + (size_t)M_TOTAL * 256;         // conv1 out -> BN+ReLU in place

    u16* zbuf = (u16*)ws;                         // 1024 B of zeros
    float* q1max = (float*)(ws + 1024);
    float* q1sum = q1max + 1;
    float* q1cnt = q1max + 2;
    float* q2max = (float*)(ws + 1088);
    float* q2sum = q2max + 1;
    float* q2cnt = q2max + 2;
    float* s1  = (float*)(ws + 1152);
    float* sq1 = s1 + 256;
    float* s2  = sq1 + 256;
    float* sq2 = s2 + 256;
    u16* wq1 = (u16*)(ws + 8192);                 // [9][256][256] bf16
    u16* wq2 = wq1 + (size_t)9 * 256 * 256;
    u16* out2 = (u16*)(ws + 2367488);             // conv2 out, 102,760,448 B

    hipMemsetAsync(ws, 0, 8192, stream);          // zbuf + q-stats + BN-stat accum

    const int nw = 256 * 256 * 9;
    k_absmax<<<512, 256, 0, stream>>>(w1, w2, nw, q1max, q2max);
    k_qsum<<<512, 256, 0, stream>>>(w1, w2, nw, q1max, q2max, q1sum, q1cnt, q2sum, q2cnt);
    k_tern<<<2 * nw / 256, 256, 0, stream>>>(w1, w2, nw, q1max, q1sum, q1cnt,
                                             q2max, q2sum, q2cnt, wq1, wq2);

    k_to_nhwc<<<dim3(1568, 4), 256, 0, stream>>>(x, xh);

    k_conv<<<3136, 256, 0, stream>>>(xh, wq1, y1, zbuf, s1, sq1);
    k_bnrelu<<<3136, 256, 0, stream>>>(y1, s1, sq1, g1, b1);

    k_conv<<<3136, 256, 0, stream>>>(y1, wq2, out2, zbuf, s2, sq2);
    k_final<<<dim3(1568, 4), 256, 0, stream>>>(out2, x, s2, sq2, g2, b2, out);
}